// Round 10
// baseline (115.820 us; speedup 1.0000x reference)
//
#include <hip/hip_runtime.h>

#define N_  128
#define C_  256
#define T_  48
#define V_  25

typedef float v4f __attribute__((ext_vector_type(4)));

// Block = (n, quad of 4 segments): 256 ch x 12 frames, 300 floats/ch = 75
// aligned float4. NO tile staging: v-means accumulated straight from the
// load stream via LDS f32 atomicAdd (chunk -> <=2 frame buckets). Gate chain
// in-block; apply re-reads x (L3-hot) and writes nontemporal float4.
__global__ __launch_bounds__(512, 4) void k_fused6(
    const float* __restrict__ x,
    const float* __restrict__ wsq, const float* __restrict__ bsq,
    const float* __restrict__ gamma, const float* __restrict__ beta,
    const float* __restrict__ rmean, const float* __restrict__ rvar,
    const float* __restrict__ wc1, const float* __restrict__ bc1,
    const float* __restrict__ wex, const float* __restrict__ bex,
    float* __restrict__ out)
{
    __shared__ float xb[256 * 12];    // frame SUMS [c][t]  (0.04 folded into BN)
    __shared__ float wsqL[256 * 17];  // wsq transposed [c][r], stride 17
    __shared__ float gs[256 * 12];    // gate [c][t]; first 384 = B1 partials
    __shared__ float ybn[192];        // [t][r]
    __shared__ float y1[192];         // [t][s]
    __shared__ float mv[192];         // [t][r]

    const int tid = threadIdx.x;
    const unsigned bid = blockIdx.x;
    const unsigned o = (bid & 7u) * 64u + (bid >> 3);   // bijective XCD chunk swizzle
    const unsigned n = o >> 2;
    const unsigned q = o & 3u;

    const unsigned base4 = n * 76800u + q * 75u;        // float4 base; + c*300 + k
    const v4f* x4 = (const v4f*)x;
    v4f*       o4 = (v4f*)out;

    // ---- prologue: zero accumulators, preload weights ----
    #pragma unroll
    for (int j = tid; j < 3072; j += 512) xb[j] = 0.f;
    #pragma unroll
    for (int it = 0; it < 8; ++it) {                    // wsq -> transposed LDS
        int j = it * 512 + tid;
        int r = j >> 8, c = j & 255;
        wsqL[c * 17 + r] = wsq[j];
    }
    float wexr[16];
    #pragma unroll
    for (int r = 0; r < 16; ++r) wexr[r] = wex[(tid & 255) * 16 + r];
    const float bexr = bex[tid & 255];
    __syncthreads();

    // ---- load + atomic frame-sum accumulation (x read #1, coalesced) ----
    for (int it = 0; it < 38; ++it) {
        int j = it * 512 + tid;                         // f4 id in tile
        if (j < 19200) {
            int c = j / 75, k = j - c * 75;
            v4f v = x4[base4 + (unsigned)(c * 300 + k)];
            int m0 = k * 4;
            int t0 = (m0 * 41) >> 10;                   // m0/25, exact m0<1024
            int t3 = ((m0 + 3) * 41) >> 10;
            float s = (v.x + v.y) + (v.z + v.w);
            if (t0 == t3) {
                atomicAdd(&xb[c * 12 + t0], s);
            } else {
                int r = 25 - (m0 - t0 * 25);            // 1..3 elems belong to t0
                float sA = v.x + ((r > 1) ? v.y : 0.f) + ((r > 2) ? v.z : 0.f);
                atomicAdd(&xb[c * 12 + t0], sA);
                atomicAdd(&xb[c * 12 + t3], s - sA);
            }
        }
    }
    __syncthreads();

    // ---- B1: squeeze partials: p = (r, t, g-half) ----
    if (tid < 384) {
        int r = tid & 15, tq = tid >> 4;                // tq 0..23
        int t = (tq >= 12) ? tq - 12 : tq;
        int g = (tq >= 12) ? 1 : 0;
        float acc = 0.f;
        #pragma unroll 8
        for (int i = 0; i < 128; ++i) {
            int c = g * 128 + i;
            acc += xb[c * 12 + t] * wsqL[c * 17 + r];
        }
        gs[tid] = acc;                                  // partials alias gs[0..384)
    }
    __syncthreads();
    // ---- B1b: combine halves + folded (0.04, bsq, BN) ----
    if (tid < 192) {
        int t = tid >> 4, r = tid & 15;
        float acc = gs[t * 16 + r] + gs[(t + 12) * 16 + r];
        float sc = gamma[r] * rsqrtf(rvar[r] + 1e-5f);
        ybn[t * 16 + r] = acc * (0.04f * sc) + (bsq[r] * sc + beta[r] - rmean[r] * sc);
    }
    __syncthreads();
    // ---- B2: conv1 ----
    if (tid < 192) {
        int t = tid >> 4, s = tid & 15;
        float acc = bc1[s];
        #pragma unroll
        for (int r = 0; r < 16; ++r) acc += ybn[t * 16 + r] * wc1[s * 16 + r];
        y1[t * 16 + s] = acc;
    }
    __syncthreads();
    // ---- B3: temporal diff (quad = 4 whole segments) ----
    if (tid < 192) {
        int t = tid >> 4, r = tid & 15;
        mv[tid] = ((t % 3) < 2) ? (y1[(t + 1) * 16 + r] - ybn[t * 16 + r]) : 0.f;
    }
    __syncthreads();
    // ---- B4: expand + sigmoid: (c, t-half) ----
    {
        int c = tid & 255, th = tid >> 8;
        #pragma unroll
        for (int t = th * 6; t < th * 6 + 6; ++t) {
            float a = bexr;
            #pragma unroll
            for (int r = 0; r < 16; ++r) a += mv[t * 16 + r] * wexr[r];
            gs[c * 12 + t] = 1.f / (1.f + expf(-a));
        }
    }
    __syncthreads();

    // ---- apply: re-read x (L3-hot), gate, nontemporal store ----
    for (int it = 0; it < 38; ++it) {
        int j = it * 512 + tid;
        if (j < 19200) {
            int c = j / 75, k = j - c * 75;
            v4f v = x4[base4 + (unsigned)(c * 300 + k)];
            int m0  = k * 4;
            int t0  = (m0 * 41) >> 10;
            int t3  = ((m0 + 3) * 41) >> 10;
            int rem = m0 - t0 * 25;
            float g0 = gs[c * 12 + t0];
            float g3 = gs[c * 12 + t3];
            v4f ov;
            ov.x = v.x * g0;
            ov.y = v.y * ((rem + 1 < 25) ? g0 : g3);
            ov.z = v.z * ((rem + 2 < 25) ? g0 : g3);
            ov.w = v.w * ((rem + 3 < 25) ? g0 : g3);
            __builtin_nontemporal_store(ov, &o4[base4 + (unsigned)(c * 300 + k)]);
        }
    }
}

extern "C" void kernel_launch(void* const* d_in, const int* in_sizes, int n_in,
                              void* d_out, int out_size, void* d_ws, size_t ws_size,
                              hipStream_t stream) {
    const float* x     = (const float*)d_in[0];
    const float* wsq   = (const float*)d_in[1];
    const float* bsq   = (const float*)d_in[2];
    const float* gamma = (const float*)d_in[3];
    const float* beta  = (const float*)d_in[4];
    const float* rmean = (const float*)d_in[5];
    const float* rvar  = (const float*)d_in[6];
    const float* wc1   = (const float*)d_in[7];
    const float* bc1   = (const float*)d_in[8];
    const float* wex   = (const float*)d_in[9];
    const float* bex   = (const float*)d_in[10];

    k_fused6<<<512, 512, 0, stream>>>(x, wsq, bsq, gamma, beta,
                                      rmean, rvar, wc1, bc1, wex, bex,
                                      (float*)d_out);
}

// Round 11
// 85.585 us; speedup vs baseline: 1.3533x; 1.3533x over previous
//
#include <hip/hip_runtime.h>

#define N_  128
#define C_  256
#define T_  48
#define V_  25

typedef float v4f __attribute__((ext_vector_type(4)));

// Block = (n, quad of 4 segments): 256 ch x 300 floats (aligned: h=0, no edges).
// Wave role-split pipeline over 16 chunks (16 ch x 75 float4 each, double-buffered):
//   waves 6,7 = producers (global float4 -> LDS), waves 0..2 = consumers (frame
//   means of previous chunk), waves 3..5 idle-at-barrier. Loads of chunk i+1 are
//   in flight while chunk i is reduced -> HBM never drains on the critical path.
// Gate math spread across all threads; BN/conv1/diff barrier-free in wave 0.
// Apply re-reads x from L3 (proven L3-resident by R10: FETCH==155MB) + NT store.
__global__ __launch_bounds__(512, 4) void k_fused7(
    const float* __restrict__ x,
    const float* __restrict__ wsq, const float* __restrict__ bsq,
    const float* __restrict__ gamma, const float* __restrict__ beta,
    const float* __restrict__ rmean, const float* __restrict__ rvar,
    const float* __restrict__ wc1, const float* __restrict__ bc1,
    const float* __restrict__ wex, const float* __restrict__ bex,
    float* __restrict__ out)
{
    __shared__ v4f   buf[2][1280];   // 40,960 B: chunk stage (1200 used + pad)
    __shared__ float xb[3072];       // frame sums [c][t]            12,288 B
    __shared__ float gs[3072];       // gate [c][t]; [0,1536) aliases B1 partials
    __shared__ float ybn[192], y1[192], mv[192];

    const int tid = threadIdx.x;
    const int wv  = tid >> 6;
    const int ln  = tid & 63;

    const unsigned bid = blockIdx.x;
    const unsigned o   = (bid & 7u) * 64u + (bid >> 3);   // bijective XCD chunk swizzle
    const unsigned n   = o >> 2;
    const unsigned qd  = o & 3u;

    const v4f* x4 = (const v4f*)x + (size_t)n * 76800u + qd * 75u;   // + c*300 + k
    v4f*       o4 = (v4f*)out     + (size_t)n * 76800u + qd * 75u;

    // producer: waves 6,7 stage chunk cg (16 ch x 75 f4) into dst
    auto stage = [&](int cg, v4f* dst) {
        const v4f* xq = x4 + cg * 4800;
        v4f tmp[10];
        #pragma unroll
        for (int i = 0; i < 10; ++i) {
            int s  = i * 128 + (wv - 6) * 64 + ln;
            int sc = (s < 1200) ? s : 1199;               // pad lanes: dup load
            int c  = sc / 75, k = sc - c * 75;
            tmp[i] = xq[c * 300 + k];
        }
        #pragma unroll
        for (int i = 0; i < 10; ++i)
            dst[i * 128 + (wv - 6) * 64 + ln] = tmp[i];
    };

    // ---- pipelined read phase: 16 chunks, double-buffered ----
    if (wv >= 6) stage(0, buf[0]);
    __syncthreads();
    for (int cg = 0; cg < 16; ++cg) {
        if (wv >= 6 && cg < 15) stage(cg + 1, buf[(cg + 1) & 1]);
        if (tid < 192) {                                   // consumer: frame sums
            int cl = tid / 12, t = tid - cl * 12;
            const float* bp = (const float*)&buf[cg & 1][cl * 75] + t * 25;
            float s = 0.f;
            #pragma unroll
            for (int v = 0; v < 25; ++v) s += bp[v];
            xb[(cg * 16 + cl) * 12 + t] = s;               // 1/25 folded into BN
        }
        __syncthreads();
    }

    // ---- B1: squeeze partials, all threads: e=(q=t*16+r)*8+g, 32 MACs each ----
    for (int e = tid; e < 1536; e += 512) {
        int g = e & 7, q = e >> 3, t = q >> 4, r = q & 15;
        const float* wrow = wsq + r * 256 + g * 32;        // L1-hot after round 1
        float acc = 0.f;
        #pragma unroll 8
        for (int i = 0; i < 32; ++i) acc += xb[(g * 32 + i) * 12 + t] * wrow[i];
        gs[e] = acc;
    }
    __syncthreads();

    // ---- wave 0 alone: combine + BN, conv1, diff (no block barriers inside) ----
    if (wv == 0) {
        #pragma unroll
        for (int j = 0; j < 3; ++j) {
            int q = ln + j * 64, r = q & 15;
            float acc = 0.f;
            #pragma unroll
            for (int g = 0; g < 8; ++g) acc += gs[q * 8 + g];
            float sc = gamma[r] * rsqrtf(rvar[r] + 1e-5f);
            ybn[q] = acc * (0.04f * sc) + (bsq[r] * sc + beta[r] - rmean[r] * sc);
        }
        #pragma unroll
        for (int j = 0; j < 3; ++j) {
            int q = ln + j * 64, t = q >> 4, s = q & 15;
            float acc = bc1[s];
            #pragma unroll
            for (int r = 0; r < 16; ++r) acc += ybn[t * 16 + r] * wc1[s * 16 + r];
            y1[q] = acc;
        }
        #pragma unroll
        for (int j = 0; j < 3; ++j) {
            int q = ln + j * 64, t = q >> 4;
            mv[q] = ((t % 3) < 2) ? (y1[q + 16] - ybn[q]) : 0.f;
        }
    }
    __syncthreads();

    // ---- B4: expand + sigmoid: (c = tid&255, t-half = tid>>8) ----
    {
        int c = tid & 255, half = tid >> 8;
        float wexr[16];
        #pragma unroll
        for (int r = 0; r < 16; ++r) wexr[r] = wex[c * 16 + r];
        float be = bex[c];
        #pragma unroll
        for (int t = half * 6; t < half * 6 + 6; ++t) {
            float a = be;
            #pragma unroll
            for (int r = 0; r < 16; ++r) a += mv[t * 16 + r] * wexr[r];
            gs[c * 12 + t] = 1.f / (1.f + expf(-a));       // overwrites B1 partials (done)
        }
    }
    __syncthreads();

    // ---- apply: re-read x (L3-hot), gate, nontemporal float4 store ----
    #pragma unroll 4
    for (int it = 0; it < 38; ++it) {
        int j = it * 512 + tid;
        if (j < 19200) {
            unsigned c = ((unsigned)j * 55926u) >> 22;      // j/75 (exact for j<19200)
            int k = j - (int)c * 75;
            v4f v = x4[c * 300 + k];
            int m0  = k * 4;
            int t0  = (m0 * 41) >> 10;                      // m0/25 (exact m0<1024)
            int t3  = ((m0 + 3) * 41) >> 10;
            int rem = m0 - t0 * 25;
            float g0 = gs[c * 12 + t0];
            float g3 = gs[c * 12 + t3];
            v4f ov;
            ov.x = v.x * g0;
            ov.y = v.y * ((rem + 1 < 25) ? g0 : g3);
            ov.z = v.z * ((rem + 2 < 25) ? g0 : g3);
            ov.w = v.w * ((rem + 3 < 25) ? g0 : g3);
            __builtin_nontemporal_store(ov, &o4[c * 300 + k]);
        }
    }
}

extern "C" void kernel_launch(void* const* d_in, const int* in_sizes, int n_in,
                              void* d_out, int out_size, void* d_ws, size_t ws_size,
                              hipStream_t stream) {
    const float* x     = (const float*)d_in[0];
    const float* wsq   = (const float*)d_in[1];
    const float* bsq   = (const float*)d_in[2];
    const float* gamma = (const float*)d_in[3];
    const float* beta  = (const float*)d_in[4];
    const float* rmean = (const float*)d_in[5];
    const float* rvar  = (const float*)d_in[6];
    const float* wc1   = (const float*)d_in[7];
    const float* bc1   = (const float*)d_in[8];
    const float* wex   = (const float*)d_in[9];
    const float* bex   = (const float*)d_in[10];

    k_fused7<<<512, 512, 0, stream>>>(x, wsq, bsq, gamma, beta,
                                      rmean, rvar, wc1, bc1, wex, bex,
                                      (float*)d_out);
}